// Round 1
// baseline (161.102 us; speedup 1.0000x reference)
//
#include <hip/hip_runtime.h>
#include <hip/hip_bf16.h>
#include <stdint.h>

// Problem constants
#define KD 2304    // K = C*3*3 = 256*9
#define LD 3136    // L = 56*56
#define ND 256     // output channels
#define MD 25088   // B*L = 8*3136
#define CD 256     // input channels

typedef __bf16 bf16x8 __attribute__((ext_vector_type(8)));
typedef float f32x4 __attribute__((ext_vector_type(4)));

__device__ __forceinline__ void gload_lds16(const void* g, void* l) {
  __builtin_amdgcn_global_load_lds(
      (const __attribute__((address_space(1))) unsigned int*)g,
      (__attribute__((address_space(3))) unsigned int*)l, 16, 0, 0);
}

// ---------------- Phase 0: weight fake-quant -> wqT [N][K] bf16 ----------------
// One block per (gk, gn) granule of 32k x 32n. w is (N, C,3,3) = [n][k] row-major.
__global__ __launch_bounds__(256) void quant_w_kernel(
    const float* __restrict__ w, __hip_bfloat16* __restrict__ wqT) {
  const int gk = blockIdx.x % 72;
  const int gn = blockIdx.x / 72;
  const int n = gn * 32 + (threadIdx.x >> 3);
  const int k = gk * 32 + (threadIdx.x & 7) * 4;
  const float4 v = *(const float4*)(w + (size_t)n * KD + k);
  float a = fmaxf(fmaxf(fabsf(v.x), fabsf(v.y)), fmaxf(fabsf(v.z), fabsf(v.w)));
#pragma unroll
  for (int m = 1; m <= 32; m <<= 1) a = fmaxf(a, __shfl_xor(a, m, 64));
  __shared__ float red[4];
  if ((threadIdx.x & 63) == 0) red[threadIdx.x >> 6] = a;
  __syncthreads();
  const float mx = fmaxf(fmaxf(red[0], red[1]), fmaxf(red[2], red[3]));
  float scale = mx / 63.f;
  if (scale == 0.f) scale = 1.f;
  const float q0 = fminf(fmaxf(rintf(v.x / scale), -63.f), 63.f);
  const float q1 = fminf(fmaxf(rintf(v.y / scale), -63.f), 63.f);
  const float q2 = fminf(fmaxf(rintf(v.z / scale), -63.f), 63.f);
  const float q3 = fminf(fmaxf(rintf(v.w / scale), -63.f), 63.f);
  ushort4 o;
  o.x = __builtin_bit_cast(unsigned short, __float2bfloat16(q0 * scale));
  o.y = __builtin_bit_cast(unsigned short, __float2bfloat16(q1 * scale));
  o.z = __builtin_bit_cast(unsigned short, __float2bfloat16(q2 * scale));
  o.w = __builtin_bit_cast(unsigned short, __float2bfloat16(q3 * scale));
  *(ushort4*)((unsigned short*)wqT + (size_t)n * KD + k) = o;
}

// ---------------- Phase 1: unfold + input fake-quant -> xq [M][K] bf16 ----------
// One wave per unfolded row (b, l). 36 chunks of 64 k; granule = 32-lane half.
__global__ __launch_bounds__(256) void quant_x_kernel(
    const float* __restrict__ x, __hip_bfloat16* __restrict__ xq) {
  const int wid = blockIdx.x * 4 + (threadIdx.x >> 6);   // row index 0..25087
  const int lane = threadIdx.x & 63;
  const int b = wid / LD;
  const int l = wid - b * LD;
  const int i = l / 56;
  const int j = l - i * 56;
  const float* xb = x + (size_t)b * CD * LD;
  __hip_bfloat16* xrow = xq + (size_t)wid * KD;
#pragma unroll 4
  for (int ch = 0; ch < 36; ++ch) {
    const int k = ch * 64 + lane;
    const int c = k / 9;
    const int kp = k - c * 9;
    const int ii = i + kp / 3 - 1;
    const int jj = j + kp % 3 - 1;
    float v = 0.f;
    if ((unsigned)ii < 56u && (unsigned)jj < 56u)
      v = xb[c * LD + ii * 56 + jj];
    float a = fabsf(v);
#pragma unroll
    for (int m = 1; m <= 16; m <<= 1) a = fmaxf(a, __shfl_xor(a, m, 64));
    float scale = a / 63.f;
    if (scale == 0.f) scale = 1.f;
    const float q = fminf(fmaxf(rintf(v / scale), -63.f), 63.f);
    xrow[k] = __float2bfloat16(q * scale);
  }
}

// ---------------- Phase 2: GEMM  out[b,n,l] = sum_k xq[m][k]*wqT[n][k] + bias[n]
// 128(n) x 128(m) block tile, BK=64, 256 threads = 4 waves (2x2), 4x4 frags/wave.
// A-operand (rows of D) = wq (n side); B-operand (cols of D) = xq (m side)
// so D's col=lane&15 dim is m -> coalesced stores in (B,N,L) layout.
__global__ __launch_bounds__(256) void gemm_kernel(
    const __hip_bfloat16* __restrict__ xq, const __hip_bfloat16* __restrict__ wqT,
    const float* __restrict__ bias, float* __restrict__ out) {
  __shared__ __hip_bfloat16 Ms[128 * 64];  // xq tile  [m_local][k]
  __shared__ __hip_bfloat16 Ns[128 * 64];  // wqT tile [n_local][k]
  const int tid = threadIdx.x;
  const int lane = tid & 63;
  const int w = tid >> 6;
  const int wr = w >> 1;  // n half
  const int wc = w & 1;   // m half
  const int m0 = blockIdx.x * 128;
  const int n1 = blockIdx.y * 128;

  f32x4 acc[4][4] = {};

  const int lrow = lane >> 3;        // 0..7
  const int lcol = (lane & 7) * 8;   // 0..56 step 8

  for (int kt = 0; kt < 36; ++kt) {
    const int k0 = kt * 64;
#pragma unroll
    for (int s = 0; s < 4; ++s) {
      const int seg = w * 4 + s;       // 0..15
      const int row = seg * 8 + lrow;  // 0..127
      gload_lds16(xq + (size_t)(m0 + row) * KD + k0 + lcol, &Ms[seg * 512 + lane * 8]);
      gload_lds16(wqT + (size_t)(n1 + row) * KD + k0 + lcol, &Ns[seg * 512 + lane * 8]);
    }
    __syncthreads();  // compiler emits vmcnt(0) drain here
#pragma unroll
    for (int kk = 0; kk < 2; ++kk) {
      const int ko = kk * 32 + (lane >> 4) * 8;
      bf16x8 af[4], bfr[4];
#pragma unroll
      for (int ifr = 0; ifr < 4; ++ifr)
        af[ifr] = *(const bf16x8*)&Ns[(wr * 64 + ifr * 16 + (lane & 15)) * 64 + ko];
#pragma unroll
      for (int jfr = 0; jfr < 4; ++jfr)
        bfr[jfr] = *(const bf16x8*)&Ms[(wc * 64 + jfr * 16 + (lane & 15)) * 64 + ko];
#pragma unroll
      for (int ifr = 0; ifr < 4; ++ifr)
#pragma unroll
        for (int jfr = 0; jfr < 4; ++jfr)
          acc[ifr][jfr] = __builtin_amdgcn_mfma_f32_16x16x32_bf16(
              af[ifr], bfr[jfr], acc[ifr][jfr], 0, 0, 0);
    }
    __syncthreads();
  }

  // Epilogue: D row = n (lane>>4)*4+r, col = m (lane&15)
  const int hv = lane >> 4;
  const int lm = lane & 15;
#pragma unroll
  for (int ifr = 0; ifr < 4; ++ifr) {
    const int nb = n1 + wr * 64 + ifr * 16 + hv * 4;
    const float4 b4 = *(const float4*)&bias[nb];
#pragma unroll
    for (int jfr = 0; jfr < 4; ++jfr) {
      const int m = m0 + wc * 64 + jfr * 16 + lm;
      const int bb = m / LD;
      const int ll = m - bb * LD;
      float* op = out + ((size_t)bb * ND + nb) * LD + ll;
      op[0]          = acc[ifr][jfr].x + b4.x;
      op[LD]         = acc[ifr][jfr].y + b4.y;
      op[2 * LD]     = acc[ifr][jfr].z + b4.z;
      op[3 * LD]     = acc[ifr][jfr].w + b4.w;
    }
  }
}

extern "C" void kernel_launch(void* const* d_in, const int* in_sizes, int n_in,
                              void* d_out, int out_size, void* d_ws, size_t ws_size,
                              hipStream_t stream) {
  const float* x = (const float*)d_in[0];
  const float* wgt = (const float*)d_in[1];
  const float* bias = (const float*)d_in[2];
  float* out = (float*)d_out;

  __hip_bfloat16* xq = (__hip_bfloat16*)d_ws;                       // 25088*2304*2 B
  __hip_bfloat16* wqT = (__hip_bfloat16*)((char*)d_ws + (size_t)MD * KD * 2);  // 256*2304*2 B

  quant_w_kernel<<<576, 256, 0, stream>>>(wgt, wqT);
  quant_x_kernel<<<MD / 4, 256, 0, stream>>>(x, xq);
  gemm_kernel<<<dim3(MD / 128, ND / 128), 256, 0, stream>>>(xq, wqT, bias, out);
}

// Round 2
// 113.725 us; speedup vs baseline: 1.4166x; 1.4166x over previous
//
#include <hip/hip_runtime.h>
#include <hip/hip_bf16.h>
#include <stdint.h>

// Problem constants
#define KD 2304    // K = C*3*3 = 256*9
#define LD 3136    // L = 56*56
#define ND 256     // output channels
#define MD 25088   // B*L = 8*3136
#define CD 256     // input channels

typedef __bf16 bf16x8 __attribute__((ext_vector_type(8)));
typedef float f32x4 __attribute__((ext_vector_type(4)));
typedef unsigned short u16x8 __attribute__((ext_vector_type(8)));

__device__ __forceinline__ void gload_lds16(const void* g, void* l) {
  __builtin_amdgcn_global_load_lds(
      (const __attribute__((address_space(1))) unsigned int*)g,
      (__attribute__((address_space(3))) unsigned int*)l, 16, 0, 0);
}

// ---------------- Phase 0: weight fake-quant -> wqT [N][K] bf16 ----------------
// One block per (gk, gn) granule of 32k x 32n. w is (N, C,3,3) = [n][k] row-major.
__global__ __launch_bounds__(256) void quant_w_kernel(
    const float* __restrict__ w, __hip_bfloat16* __restrict__ wqT) {
  const int gk = blockIdx.x % 72;
  const int gn = blockIdx.x / 72;
  const int n = gn * 32 + (threadIdx.x >> 3);
  const int k = gk * 32 + (threadIdx.x & 7) * 4;
  const float4 v = *(const float4*)(w + (size_t)n * KD + k);
  float a = fmaxf(fmaxf(fabsf(v.x), fabsf(v.y)), fmaxf(fabsf(v.z), fabsf(v.w)));
#pragma unroll
  for (int m = 1; m <= 32; m <<= 1) a = fmaxf(a, __shfl_xor(a, m, 64));
  __shared__ float red[4];
  if ((threadIdx.x & 63) == 0) red[threadIdx.x >> 6] = a;
  __syncthreads();
  const float mx = fmaxf(fmaxf(red[0], red[1]), fmaxf(red[2], red[3]));
  const float r63 = (mx == 0.f) ? 0.f : 63.f / mx;
  const float scale = mx * (1.f / 63.f);
  float q0 = fminf(fmaxf(rintf(v.x * r63), -63.f), 63.f);
  float q1 = fminf(fmaxf(rintf(v.y * r63), -63.f), 63.f);
  float q2 = fminf(fmaxf(rintf(v.z * r63), -63.f), 63.f);
  float q3 = fminf(fmaxf(rintf(v.w * r63), -63.f), 63.f);
  ushort4 o;
  o.x = __builtin_bit_cast(unsigned short, __float2bfloat16(q0 * scale));
  o.y = __builtin_bit_cast(unsigned short, __float2bfloat16(q1 * scale));
  o.z = __builtin_bit_cast(unsigned short, __float2bfloat16(q2 * scale));
  o.w = __builtin_bit_cast(unsigned short, __float2bfloat16(q3 * scale));
  *(ushort4*)((unsigned short*)wqT + (size_t)n * KD + k) = o;
}

// ---------------- Phase 1: unfold + input fake-quant -> xq [M][K] bf16 ----------
// One THREAD per (row, k-granule): serial in-register 32-elem max (no shuffles),
// hoisted reciprocal (one 63/mx fdiv per granule). Rows map to lanes -> x loads
// are coalesced (adjacent rows = adjacent j). Granule index is wave-uniform ->
// tap/channel walk lives on the scalar pipe.
__global__ __launch_bounds__(256) void quant_x_kernel(
    const float* __restrict__ x, __hip_bfloat16* __restrict__ xq) {
  const int lane = threadIdx.x & 63;
  const int row = blockIdx.x * 64 + lane;                 // 0..25087 (chunks never straddle b: 3136/64=49)
  const int g = __builtin_amdgcn_readfirstlane(blockIdx.y * 4 + (threadIdx.x >> 6)); // 0..71, wave-uniform
  const int b = row / LD;
  const int l = row - b * LD;
  const int i = l / 56;
  const int j = l - i * 56;
  const float* pb = x + (size_t)b * CD * LD;
  const int p0 = i * 56 + j;

  const bool iN = (i > 0), iS = (i < 55), jW = (j > 0), jE = (j < 55);

  const int k0 = g * 32;
  int c = k0 / 9;
  int kp = k0 - 9 * c;

  float v[32];
  float mx = 0.f;
#pragma unroll
  for (int t = 0; t < 32; ++t) {
    const int di = (kp >= 6) ? 2 : ((kp >= 3) ? 1 : 0);
    const int dj = kp - 3 * di;
    const bool oki = (di == 0) ? iN : ((di == 2) ? iS : true);
    const bool okj = (dj == 0) ? jW : ((dj == 2) ? jE : true);
    const bool ok = oki && okj;
    const int off = c * LD + (di - 1) * 56 + (dj - 1);    // wave-uniform scalar
    float val = pb[p0 + (ok ? off : 0)];                  // clamped addr stays in-bounds
    val = ok ? val : 0.f;
    v[t] = val;
    mx = fmaxf(mx, __builtin_fabsf(val));
    if (++kp == 9) { kp = 0; ++c; }
  }

  const float r63 = (mx == 0.f) ? 0.f : 63.f / mx;
  const float scale = mx * (1.f / 63.f);
  unsigned short* dst = (unsigned short*)xq + (size_t)row * KD + k0;
#pragma unroll
  for (int s = 0; s < 4; ++s) {
    u16x8 o;
#pragma unroll
    for (int e = 0; e < 8; ++e) {
      float q = rintf(v[s * 8 + e] * r63);
      q = fminf(fmaxf(q, -63.f), 63.f);
      o[e] = __builtin_bit_cast(unsigned short, __float2bfloat16(q * scale));
    }
    *((u16x8*)dst + s) = o;
  }
}

// ---------------- Phase 2: GEMM  out[b,n,l] = sum_k xq[m][k]*wqT[n][k] + bias[n]
// 128(n) x 128(m) block tile, BK=64, 256 threads = 4 waves (2x2), 4x4 frags/wave.
// A-operand (rows of D) = wq (n side); B-operand (cols of D) = xq (m side)
// so D's col=lane&15 dim is m -> coalesced stores in (B,N,L) layout.
__global__ __launch_bounds__(256) void gemm_kernel(
    const __hip_bfloat16* __restrict__ xq, const __hip_bfloat16* __restrict__ wqT,
    const float* __restrict__ bias, float* __restrict__ out) {
  __shared__ __hip_bfloat16 Ms[128 * 64];  // xq tile  [m_local][k]
  __shared__ __hip_bfloat16 Ns[128 * 64];  // wqT tile [n_local][k]
  const int tid = threadIdx.x;
  const int lane = tid & 63;
  const int w = tid >> 6;
  const int wr = w >> 1;  // n half
  const int wc = w & 1;   // m half
  const int m0 = blockIdx.x * 128;
  const int n1 = blockIdx.y * 128;

  f32x4 acc[4][4] = {};

  const int lrow = lane >> 3;        // 0..7
  const int lcol = (lane & 7) * 8;   // 0..56 step 8

  for (int kt = 0; kt < 36; ++kt) {
    const int k0 = kt * 64;
#pragma unroll
    for (int s = 0; s < 4; ++s) {
      const int seg = w * 4 + s;       // 0..15
      const int row = seg * 8 + lrow;  // 0..127
      gload_lds16(xq + (size_t)(m0 + row) * KD + k0 + lcol, &Ms[seg * 512 + lane * 8]);
      gload_lds16(wqT + (size_t)(n1 + row) * KD + k0 + lcol, &Ns[seg * 512 + lane * 8]);
    }
    __syncthreads();
#pragma unroll
    for (int kk = 0; kk < 2; ++kk) {
      const int ko = kk * 32 + (lane >> 4) * 8;
      bf16x8 af[4], bfr[4];
#pragma unroll
      for (int ifr = 0; ifr < 4; ++ifr)
        af[ifr] = *(const bf16x8*)&Ns[(wr * 64 + ifr * 16 + (lane & 15)) * 64 + ko];
#pragma unroll
      for (int jfr = 0; jfr < 4; ++jfr)
        bfr[jfr] = *(const bf16x8*)&Ms[(wc * 64 + jfr * 16 + (lane & 15)) * 64 + ko];
#pragma unroll
      for (int ifr = 0; ifr < 4; ++ifr)
#pragma unroll
        for (int jfr = 0; jfr < 4; ++jfr)
          acc[ifr][jfr] = __builtin_amdgcn_mfma_f32_16x16x32_bf16(
              af[ifr], bfr[jfr], acc[ifr][jfr], 0, 0, 0);
    }
    __syncthreads();
  }

  // Epilogue: D row = n (lane>>4)*4+r, col = m (lane&15)
  const int hv = lane >> 4;
  const int lm = lane & 15;
#pragma unroll
  for (int ifr = 0; ifr < 4; ++ifr) {
    const int nb = n1 + wr * 64 + ifr * 16 + hv * 4;
    const float4 b4 = *(const float4*)&bias[nb];
#pragma unroll
    for (int jfr = 0; jfr < 4; ++jfr) {
      const int m = m0 + wc * 64 + jfr * 16 + lm;
      const int bb = m / LD;
      const int ll = m - bb * LD;
      float* op = out + ((size_t)bb * ND + nb) * LD + ll;
      op[0]          = acc[ifr][jfr].x + b4.x;
      op[LD]         = acc[ifr][jfr].y + b4.y;
      op[2 * LD]     = acc[ifr][jfr].z + b4.z;
      op[3 * LD]     = acc[ifr][jfr].w + b4.w;
    }
  }
}

extern "C" void kernel_launch(void* const* d_in, const int* in_sizes, int n_in,
                              void* d_out, int out_size, void* d_ws, size_t ws_size,
                              hipStream_t stream) {
  const float* x = (const float*)d_in[0];
  const float* wgt = (const float*)d_in[1];
  const float* bias = (const float*)d_in[2];
  float* out = (float*)d_out;

  __hip_bfloat16* xq = (__hip_bfloat16*)d_ws;                       // 25088*2304*2 B
  __hip_bfloat16* wqT = (__hip_bfloat16*)((char*)d_ws + (size_t)MD * KD * 2);  // 256*2304*2 B

  quant_w_kernel<<<576, 256, 0, stream>>>(wgt, wqT);
  quant_x_kernel<<<dim3(MD / 64, 18), 256, 0, stream>>>(x, xq);
  gemm_kernel<<<dim3(MD / 128, ND / 128), 256, 0, stream>>>(xq, wqT, bias, out);
}